// Round 11
// baseline (230.034 us; speedup 1.0000x reference)
//
#include <hip/hip_runtime.h>

// VQ-VAE vector quantizer: B=32768, K=4096, D=256 (fp32)
// out = [quantized (B*D floats), vq_loss (1 float)]
//
//  xconv : X -> fp16 (hi only), 64-row-block frag tiles into d_out (16MB, overwritten later)
//  econv : E -> NEGATED fp16 (hi only), linear 4KB tiles (ct64 x kb8) in ws
//  en2   : en2f[k] = 0.5*||E_k||^2 exact fp32 into ws
//  dist11: barrier-free hi-only GEMM, ONE 768-thr block (12 waves) per CU.
//          X (32KB) + en2 (16KB) LDS-shared; each wave owns 5-6 contiguous
//          64-code ctiles, stages its E tiles wave-private (8KB dbuf, linear
//          addresses, counted vmcnt(4), no barriers). Wave tile 64r x 64c,
//          16 MFMA/phase. Epilogue: argmin-of-4-j first, then one top-2 update.
//          Groups: waves 0-5 / 6-11 -> top-2 per group (4 candidates/row).
//  rescore: fp64 rescore of 4 candidates -> exact winner, gather, loss partials
//  finalize: loss = 1.25 * mean((x-q)^2)

#define B_N 32768
#define K_N 4096
#define D_N 256

typedef _Float16 f16x8 __attribute__((ext_vector_type(8)));
typedef float f32x4 __attribute__((ext_vector_type(4)));
typedef unsigned int uint4v __attribute__((ext_vector_type(4)));
typedef unsigned short u16;

// ws layout (~3.1 MB)
static constexpr size_t P_TOP2 = 0;                               // 32768*2*16 = 1 MB
static constexpr size_t P_ESW  = (size_t)B_N * 2 * 16;            // +2 MB
static constexpr size_t P_EN2  = P_ESW + (size_t)K_N * D_N * 2;   // +16 KB
static constexpr size_t P_PART = P_EN2 + (size_t)K_N * 4;         // +4 KB

__device__ __forceinline__ u16 f2h(float f) {
    _Float16 h = (_Float16)f;
    return __builtin_bit_cast(u16, h);
}

__device__ __forceinline__ void gload_lds16(const void* g, void* l) {
    __builtin_amdgcn_global_load_lds(
        (const __attribute__((address_space(1))) void*)g,
        (__attribute__((address_space(3))) void*)l, 16, 0, 0);
}

#define WAITVM(N) asm volatile("s_waitcnt vmcnt(" #N ")" ::: "memory")
#define BARRIER() __builtin_amdgcn_s_barrier()

__device__ __forceinline__ void top2_merge(float& v0, int& i0, float& v1, int& i1,
                                           float ov0, int oi0, float ov1, int oi1) {
    bool bf_ = (ov0 < v0) || (ov0 == v0 && oi0 < i0);
    float w0v = bf_ ? ov0 : v0;  int w0i = bf_ ? oi0 : i0;
    float lv  = bf_ ? v0  : ov0; int li  = bf_ ? i0  : oi0;
    float cv  = bf_ ? ov1 : v1;  int ci  = bf_ ? oi1 : i1;
    bool tl = (lv < cv) || (lv == cv && li < ci);
    v0 = w0v; i0 = w0i;
    v1 = tl ? lv : cv; i1 = tl ? li : ci;
}

// ---------- xconv: X -> fp16 hi, 64-row-block tiles ----------
// u16 index = rb*16384 + kb*2048 + rf*512 + lane*8
// row = rb*64 + rf*16 + llo ; d = kb*32 + lhi*8 + j ; lane = lhi*16+llo
__global__ void xconv_kernel(const float* __restrict__ X, u16* __restrict__ Xsw) {
    const int gid = blockIdx.x * 256 + threadIdx.x;     // B_N*32 threads
    const int row = gid >> 5;
    const int d0  = (gid & 31) << 3;
    const float4 a = *reinterpret_cast<const float4*>(X + (size_t)row * D_N + d0);
    const float4 b = *reinterpret_cast<const float4*>(X + (size_t)row * D_N + d0 + 4);
    float f[8] = {a.x, a.y, a.z, a.w, b.x, b.y, b.z, b.w};
    unsigned hi[8];
    #pragma unroll
    for (int j = 0; j < 8; ++j) hi[j] = f2h(f[j]);
    const int rb = row >> 6, rr = row & 63, rf = rr >> 4, llo = rr & 15;
    const int kb = d0 >> 5, lhi = (d0 & 31) >> 3, lane = lhi * 16 + llo;
    size_t base = (size_t)rb * 16384 + (size_t)kb * 2048 + (size_t)rf * 512 + (size_t)lane * 8;
    uint4v hv;
    hv.x = hi[0] | (hi[1] << 16); hv.y = hi[2] | (hi[3] << 16);
    hv.z = hi[4] | (hi[5] << 16); hv.w = hi[6] | (hi[7] << 16);
    *reinterpret_cast<uint4v*>(Xsw + base) = hv;
}

// ---------- econv: E -> negated fp16 hi, linear (ct,kb) 4KB tiles ----------
// code = ct*64 + cf*16 + llo ; u16 index = ((ct*8+kb)*4 + cf)*512 + lane*8
__global__ void econv_kernel(const float* __restrict__ E, u16* __restrict__ Esw) {
    const int gid = blockIdx.x * 256 + threadIdx.x;     // K_N*32 threads
    const int code = gid >> 5;
    const int d0  = (gid & 31) << 3;
    const float4 a = *reinterpret_cast<const float4*>(E + (size_t)code * D_N + d0);
    const float4 b = *reinterpret_cast<const float4*>(E + (size_t)code * D_N + d0 + 4);
    float f[8] = {a.x, a.y, a.z, a.w, b.x, b.y, b.z, b.w};
    unsigned hi[8];
    #pragma unroll
    for (int j = 0; j < 8; ++j) hi[j] = f2h(-f[j]);
    const int ct = code >> 6, cf = (code >> 4) & 3, llo = code & 15;
    const int kb = d0 >> 5, lhi = (d0 & 31) >> 3, lane = lhi * 16 + llo;
    size_t base = ((size_t)((ct * 8 + kb) * 4 + cf)) * 512 + (size_t)lane * 8;
    uint4v hv;
    hv.x = hi[0] | (hi[1] << 16); hv.y = hi[2] | (hi[3] << 16);
    hv.z = hi[4] | (hi[5] << 16); hv.w = hi[6] | (hi[7] << 16);
    *reinterpret_cast<uint4v*>(Esw + base) = hv;
}

// ---------- en2: exact fp32 0.5||e||^2 ----------
__global__ void en2_kernel(const float* __restrict__ E, float* __restrict__ en2f) {
    const int gtid = blockIdx.x * blockDim.x + threadIdx.x;
    const int code = gtid >> 6;
    const int lane = threadIdx.x & 63;
    if (code >= K_N) return;
    const float4 v = *reinterpret_cast<const float4*>(E + (size_t)code * D_N + lane * 4);
    double s = (double)v.x * v.x + (double)v.y * v.y + (double)v.z * v.z + (double)v.w * v.w;
    #pragma unroll
    for (int o = 32; o; o >>= 1) s += __shfl_xor(s, o, 64);
    if (lane == 0) en2f[code] = (float)(0.5 * s);
}

// ---------- dist11: 12-wave mega-block, barrier-free, X+en2 shared ----------
// 512 blocks x 768 thr (12 waves). Wave w owns ctiles [ct0, ct0+ncw) of 64 codes.
// LDS 147456 B: X 32KB @0 ; E stage 12 x 8KB dbuf @32768 ; en2 fp32[4096] @131072.
__launch_bounds__(768, 1)
__global__ void dist11_kernel(const char* __restrict__ Xsw, const char* __restrict__ Esw,
                              const float* __restrict__ en2f, float4* __restrict__ top2) {
    __shared__ __align__(16) char lds[147456];
    const int tid  = threadIdx.x;
    const int lane = tid & 63;
    const int wid  = tid >> 6;          // 0..11
    const int llo  = lane & 15, lhi = lane >> 4;
    const int rb = blockIdx.x;          // 0..511 (64-row group)

    const int ncw = (wid < 4) ? 6 : 5;
    const int ct0 = (wid < 4) ? wid * 6 : 24 + (wid - 4) * 5;
    const int nph = ncw * 8;

    const char* xb = Xsw + (size_t)rb * 32768;
    const char* eb = Esw + (size_t)ct0 * 8 * 4096;    // linear tiles for this wave
    char* ldsE = lds + 32768 + wid * 8192;

    auto STAGE = [&](int p) {   // stage tile p (4KB) into parity p&1
        const char* es = eb + (size_t)p * 4096;
        char* lb = ldsE + (p & 1) * 4096;
        gload_lds16(es + lane * 16,        lb);
        gload_lds16(es + 1024 + lane * 16, lb + 1024);
        gload_lds16(es + 2048 + lane * 16, lb + 2048);
        gload_lds16(es + 3072 + lane * 16, lb + 3072);
    };

    float tv0[16], tv1[16];
    int   tpk[16];
    #pragma unroll
    for (int s = 0; s < 16; ++s) { tv0[s] = 3.4e38f; tv1[s] = 3.4e38f; tpk[s] = -1; }

    f32x4 acc[4][4];
    #pragma unroll
    for (int i = 0; i < 4; ++i)
        #pragma unroll
        for (int j = 0; j < 4; ++j) acc[i][j] = (f32x4){0.f, 0.f, 0.f, 0.f};

    // prologue: X (32 chunks) + en2 (16 chunks) to LDS, first E tile
    for (int c = wid; c < 32; c += 12)
        gload_lds16(xb + c * 1024 + lane * 16, lds + c * 1024);
    const char* en2c = reinterpret_cast<const char*>(en2f);
    for (int c = wid; c < 16; c += 12)
        gload_lds16(en2c + c * 1024 + lane * 16, lds + 131072 + c * 1024);
    STAGE(0);
    WAITVM(0);
    BARRIER();      // X + en2 visible to all waves

    const f16x8* LX = reinterpret_cast<const f16x8*>(lds);
    const float* ENL = reinterpret_cast<const float*>(lds + 131072);

    for (int ci = 0; ci < ncw; ++ci) {
        const int ct = ct0 + ci;
        float en[4];
        #pragma unroll
        for (int j = 0; j < 4; ++j) en[j] = ENL[ct * 64 + j * 16 + llo];
        const int idxbase = ct * 64 + llo;

        #pragma unroll
        for (int kb = 0; kb < 8; ++kb) {
            const int p = ci * 8 + kb;
            if (p + 1 < nph) { STAGE(p + 1); WAITVM(4); }
            else             { WAITVM(0); }

            f16x8 ev[4];
            #pragma unroll
            for (int j = 0; j < 4; ++j)
                ev[j] = *reinterpret_cast<const f16x8*>(
                    ldsE + (p & 1) * 4096 + j * 1024 + lane * 16);

            __builtin_amdgcn_s_setprio(1);
            f16x8 av[4];
            #pragma unroll
            for (int i = 0; i < 4; ++i)
                av[i] = LX[(kb * 4 + i) * 64 + lane];
            #pragma unroll
            for (int i = 0; i < 4; ++i)
                #pragma unroll
                for (int j = 0; j < 4; ++j)
                    acc[i][j] = __builtin_amdgcn_mfma_f32_16x16x32_f16(
                        av[i], ev[j], acc[i][j], 0, 0, 0);
            __builtin_amdgcn_s_setprio(0);

            if (kb == 7) {
                // epilogue: per slot, argmin over the 4 j-candidates, then one top-2 update
                #pragma unroll
                for (int i = 0; i < 4; ++i) {
                    #pragma unroll
                    for (int r = 0; r < 4; ++r) {
                        const int s = i * 4 + r;
                        const float v0c = en[0] + acc[i][0][r];
                        const float v1c = en[1] + acc[i][1][r];
                        const float v2c = en[2] + acc[i][2][r];
                        const float v3c = en[3] + acc[i][3][r];
                        const bool cA = v1c < v0c;
                        const float mA = cA ? v1c : v0c; const int jA = cA ? 1 : 0;
                        const bool cB = v3c < v2c;
                        const float mB = cB ? v3c : v2c; const int jB = cB ? 3 : 2;
                        const bool cC = mB < mA;
                        const float mv = cC ? mB : mA;   const int jm = cC ? jB : jA;
                        const int idx = idxbase + (jm << 4);
                        const bool c0 = mv < tv0[s];
                        const bool c1 = mv < tv1[s];
                        const int pk = tpk[s];
                        const int pkA = (pk << 16) | idx;
                        const int pkB = (idx << 16) | (pk & 0xffff);
                        tv1[s] = c0 ? tv0[s] : (c1 ? mv : tv1[s]);
                        tv0[s] = c0 ? mv : tv0[s];
                        tpk[s] = c0 ? pkA : (c1 ? pkB : pk);
                    }
                }
                #pragma unroll
                for (int i = 0; i < 4; ++i)
                    #pragma unroll
                    for (int j = 0; j < 4; ++j) acc[i][j] = (f32x4){0.f, 0.f, 0.f, 0.f};
            }
        }
    }

    // merge the 16 column-lanes (llo) via shfl butterfly
    #pragma unroll
    for (int m = 1; m <= 8; m <<= 1) {
        #pragma unroll
        for (int s = 0; s < 16; ++s) {
            float ov0 = __shfl_xor(tv0[s], m, 64);
            float ov1 = __shfl_xor(tv1[s], m, 64);
            int   opk = __shfl_xor(tpk[s], m, 64);
            float v0 = tv0[s], v1 = tv1[s];
            int i0 = tpk[s] & 0xffff, i1 = (tpk[s] >> 16) & 0xffff;
            top2_merge(v0, i0, v1, i1, ov0, opk & 0xffff, ov1, (opk >> 16) & 0xffff);
            tv0[s] = v0; tv1[s] = v1; tpk[s] = (i1 << 16) | i0;
        }
    }

    BARRIER();      // all waves done reading X -> safe to reuse X region
    float4* M = reinterpret_cast<float4*>(lds);   // [64 rows][12 waves]
    if (llo == 0) {
        #pragma unroll
        for (int i = 0; i < 4; ++i)
            #pragma unroll
            for (int r = 0; r < 4; ++r) {
                const int rowl = i * 16 + lhi * 4 + r;
                const int s = i * 4 + r;
                M[rowl * 12 + wid] = make_float4(tv0[s], __int_as_float(tpk[s] & 0xffff),
                                                 tv1[s], __int_as_float((tpk[s] >> 16) & 0xffff));
            }
    }
    __syncthreads();
    if (tid < 64) {
        // groups: waves 0-5 -> entry 0, waves 6-11 -> entry 1
        #pragma unroll
        for (int g = 0; g < 2; ++g) {
            float4 A4 = M[tid * 12 + g * 6];
            float v0 = A4.x, v1 = A4.z;
            int i0 = __float_as_int(A4.y), i1 = __float_as_int(A4.w);
            #pragma unroll
            for (int w = 1; w < 6; ++w) {
                float4 Bw = M[tid * 12 + g * 6 + w];
                top2_merge(v0, i0, v1, i1, Bw.x, __float_as_int(Bw.y),
                           Bw.z, __float_as_int(Bw.w));
            }
            top2[(size_t)(rb * 64 + tid) * 2 + g] =
                make_float4(v0, __int_as_float(i0), v1, __int_as_float(i1));
        }
    }
}

// ---------- rescore: fp64 rescore of 4 candidates (2 per group) ----------
__global__ void rescore_kernel(const float* __restrict__ X, const float* __restrict__ E,
                               const float4* __restrict__ top2, float* __restrict__ out,
                               double* __restrict__ partials) {
    const int lane = threadIdx.x & 63;
    const int wid  = (blockIdx.x * blockDim.x + threadIdx.x) >> 6;
    const int nw   = (gridDim.x * blockDim.x) >> 6;
    double wloc = 0.0;

    for (int row = wid; row < B_N; row += nw) {
        float4 t0 = top2[(size_t)row * 2 + 0];
        float4 t1 = top2[(size_t)row * 2 + 1];
        int cand[4] = { __float_as_int(t0.y), __float_as_int(t0.w),
                        __float_as_int(t1.y), __float_as_int(t1.w) };
        const float4 xv = *reinterpret_cast<const float4*>(X + (size_t)row * D_N + lane * 4);

        double bestd = 1e300; int besti = 0x7fffffff;
        float4 beste = make_float4(0.f, 0.f, 0.f, 0.f);
        #pragma unroll
        for (int c = 0; c < 4; ++c) {
            const int k = cand[c];
            const float4 ev = *reinterpret_cast<const float4*>(E + (size_t)k * D_N + lane * 4);
            double dx = (double)xv.x - (double)ev.x;
            double dy = (double)xv.y - (double)ev.y;
            double dz = (double)xv.z - (double)ev.z;
            double dw = (double)xv.w - (double)ev.w;
            double s = dx * dx + dy * dy + dz * dz + dw * dw;
            #pragma unroll
            for (int o = 32; o; o >>= 1) s += __shfl_xor(s, o, 64);
            if (s < bestd || (s == bestd && k < besti)) { bestd = s; besti = k; beste = ev; }
        }
        *reinterpret_cast<float4*>(out + (size_t)row * D_N + lane * 4) = beste;
        wloc += bestd;
    }

    __shared__ double bsum[8];
    const int widx = threadIdx.x >> 6;
    if (lane == 0) bsum[widx] = wloc;
    __syncthreads();
    if (threadIdx.x == 0) {
        double s = 0.0;
        for (int w = 0; w < (int)(blockDim.x >> 6); ++w) s += bsum[w];
        partials[blockIdx.x] = s;
    }
}

__global__ void finalize_kernel(const double* __restrict__ partials, int n,
                                float* __restrict__ loss_out) {
    __shared__ double sm[256];
    double s = 0.0;
    for (int i = threadIdx.x; i < n; i += 256) s += partials[i];
    sm[threadIdx.x] = s;
    __syncthreads();
    for (int st = 128; st; st >>= 1) {
        if (threadIdx.x < st) sm[threadIdx.x] += sm[threadIdx.x + st];
        __syncthreads();
    }
    if (threadIdx.x == 0)
        *loss_out = (float)(1.25 * sm[0] / (double)((size_t)B_N * D_N));
}

extern "C" void kernel_launch(void* const* d_in, const int* in_sizes, int n_in,
                              void* d_out, int out_size, void* d_ws, size_t ws_size,
                              hipStream_t stream) {
    const float* X = (const float*)d_in[0];
    const float* E = (const float*)d_in[1];
    float* out = (float*)d_out;
    char* ws = (char*)d_ws;

    u16*    Xsw      = (u16*)d_out;          // 16 MiB scratch in d_out (overwritten by rescore)
    float4* top2     = (float4*)(ws + P_TOP2);
    u16*    Esw      = (u16*)(ws + P_ESW);
    float*  en2f     = (float*)(ws + P_EN2);
    double* partials = (double*)(ws + P_PART);

    xconv_kernel<<<(B_N * 32) / 256, 256, 0, stream>>>(X, Xsw);
    econv_kernel<<<(K_N * 32) / 256, 256, 0, stream>>>(E, Esw);
    en2_kernel<<<K_N / 4, 256, 0, stream>>>(E, en2f);
    dist11_kernel<<<B_N / 64, 768, 0, stream>>>(
        (const char*)Xsw, (const char*)Esw, en2f, top2);
    rescore_kernel<<<512, 256, 0, stream>>>(X, E, top2, out, partials);
    finalize_kernel<<<1, 256, 0, stream>>>(partials, 512, out + (size_t)B_N * D_N);
}

// Round 12
// 149.318 us; speedup vs baseline: 1.5406x; 1.5406x over previous
//
#include <hip/hip_runtime.h>

// VQ-VAE vector quantizer: B=32768, K=4096, D=256 (fp32)
// out = [quantized (B*D floats), vq_loss (1 float)]
//
//  xconv : X -> fp16 (hi only), 64-row-block frag tiles into d_out (16MB, overwritten later)
//  econv : E -> NEGATED fp16 (hi only), per-(ct,q,kb) 4KB frag tiles in ws
//  en2   : en2f[k] = 0.5*||E_k||^2 exact fp32 into ws
//  dist12: R10 structure (barrier-free, X+en2 LDS-resident, E wave-private staged,
//          4 waves x 64r x 64c, vmcnt(4) counted) with PACKED-U32 argmin epilogue:
//          v' = en2 + 512 - x.e > 0 ; packed = (bits(v') & ~63) | (ct*4+j) ;
//          per-slot top-2 via min/max u32 (6 VALU/candidate vs 13).
//          Decode to (val,idx) once before the cross-lane butterfly.
//  rescore: fp64 rescore of 4 candidates -> exact winner, gather, loss partials
//  finalize: loss = 1.25 * mean((x-q)^2)

#define B_N 32768
#define K_N 4096
#define D_N 256

typedef _Float16 f16x8 __attribute__((ext_vector_type(8)));
typedef float f32x4 __attribute__((ext_vector_type(4)));
typedef unsigned int uint4v __attribute__((ext_vector_type(4)));
typedef unsigned short u16;

// ws layout (~3.1 MB)
static constexpr size_t P_TOP2 = 0;                               // 32768*2*16 = 1 MB
static constexpr size_t P_ESW  = (size_t)B_N * 2 * 16;            // +2 MB
static constexpr size_t P_EN2  = P_ESW + (size_t)K_N * D_N * 2;   // +16 KB
static constexpr size_t P_PART = P_EN2 + (size_t)K_N * 4;         // +4 KB

__device__ __forceinline__ u16 f2h(float f) {
    _Float16 h = (_Float16)f;
    return __builtin_bit_cast(u16, h);
}

__device__ __forceinline__ void gload_lds16(const void* g, void* l) {
    __builtin_amdgcn_global_load_lds(
        (const __attribute__((address_space(1))) void*)g,
        (__attribute__((address_space(3))) void*)l, 16, 0, 0);
}

#define WAITVM(N) asm volatile("s_waitcnt vmcnt(" #N ")" ::: "memory")
#define BARRIER() __builtin_amdgcn_s_barrier()

__device__ __forceinline__ void top2_merge(float& v0, int& i0, float& v1, int& i1,
                                           float ov0, int oi0, float ov1, int oi1) {
    bool bf_ = (ov0 < v0) || (ov0 == v0 && oi0 < i0);
    float w0v = bf_ ? ov0 : v0;  int w0i = bf_ ? oi0 : i0;
    float lv  = bf_ ? v0  : ov0; int li  = bf_ ? i0  : oi0;
    float cv  = bf_ ? ov1 : v1;  int ci  = bf_ ? oi1 : i1;
    bool tl = (lv < cv) || (lv == cv && li < ci);
    v0 = w0v; i0 = w0i;
    v1 = tl ? lv : cv; i1 = tl ? li : ci;
}

// ---------- xconv: X -> fp16 hi, 64-row-block tiles ----------
// u16 index = rb*16384 + kb*2048 + rf*512 + lane*8
// row = rb*64 + rf*16 + llo ; d = kb*32 + lhi*8 + j ; lane = lhi*16+llo
__global__ void xconv_kernel(const float* __restrict__ X, u16* __restrict__ Xsw) {
    const int gid = blockIdx.x * 256 + threadIdx.x;     // B_N*32 threads
    const int row = gid >> 5;
    const int d0  = (gid & 31) << 3;
    const float4 a = *reinterpret_cast<const float4*>(X + (size_t)row * D_N + d0);
    const float4 b = *reinterpret_cast<const float4*>(X + (size_t)row * D_N + d0 + 4);
    float f[8] = {a.x, a.y, a.z, a.w, b.x, b.y, b.z, b.w};
    unsigned hi[8];
    #pragma unroll
    for (int j = 0; j < 8; ++j) hi[j] = f2h(f[j]);
    const int rb = row >> 6, rr = row & 63, rf = rr >> 4, llo = rr & 15;
    const int kb = d0 >> 5, lhi = (d0 & 31) >> 3, lane = lhi * 16 + llo;
    size_t base = (size_t)rb * 16384 + (size_t)kb * 2048 + (size_t)rf * 512 + (size_t)lane * 8;
    uint4v hv;
    hv.x = hi[0] | (hi[1] << 16); hv.y = hi[2] | (hi[3] << 16);
    hv.z = hi[4] | (hi[5] << 16); hv.w = hi[6] | (hi[7] << 16);
    *reinterpret_cast<uint4v*>(Xsw + base) = hv;
}

// ---------- econv: E -> negated fp16 hi, per-(ct,q,kb) 4KB tiles ----------
// code = ct*256 + q*64 + cf*16 + llo ; u16 index = (((ct*4+q)*8+kb)*4 + cf)*512 + lane*8
__global__ void econv_kernel(const float* __restrict__ E, u16* __restrict__ Esw) {
    const int gid = blockIdx.x * 256 + threadIdx.x;     // K_N*32 threads
    const int code = gid >> 5;
    const int d0  = (gid & 31) << 3;
    const float4 a = *reinterpret_cast<const float4*>(E + (size_t)code * D_N + d0);
    const float4 b = *reinterpret_cast<const float4*>(E + (size_t)code * D_N + d0 + 4);
    float f[8] = {a.x, a.y, a.z, a.w, b.x, b.y, b.z, b.w};
    unsigned hi[8];
    #pragma unroll
    for (int j = 0; j < 8; ++j) hi[j] = f2h(-f[j]);
    const int ct = code >> 8, q = (code >> 6) & 3, cf = (code >> 4) & 3, llo = code & 15;
    const int kb = d0 >> 5, lhi = (d0 & 31) >> 3, lane = lhi * 16 + llo;
    size_t base = ((size_t)(((ct * 4 + q) * 8 + kb) * 4 + cf)) * 512 + (size_t)lane * 8;
    uint4v hv;
    hv.x = hi[0] | (hi[1] << 16); hv.y = hi[2] | (hi[3] << 16);
    hv.z = hi[4] | (hi[5] << 16); hv.w = hi[6] | (hi[7] << 16);
    *reinterpret_cast<uint4v*>(Esw + base) = hv;
}

// ---------- en2: exact fp32 0.5||e||^2 ----------
__global__ void en2_kernel(const float* __restrict__ E, float* __restrict__ en2f) {
    const int gtid = blockIdx.x * blockDim.x + threadIdx.x;
    const int code = gtid >> 6;
    const int lane = threadIdx.x & 63;
    if (code >= K_N) return;
    const float4 v = *reinterpret_cast<const float4*>(E + (size_t)code * D_N + lane * 4);
    double s = (double)v.x * v.x + (double)v.y * v.y + (double)v.z * v.z + (double)v.w * v.w;
    #pragma unroll
    for (int o = 32; o; o >>= 1) s += __shfl_xor(s, o, 64);
    if (lane == 0) en2f[code] = (float)(0.5 * s);
}

// ---------- dist12: barrier-free, X+en2 LDS-resident, packed-u32 epilogue ----------
// 512 blocks, 256 thr = 4 waves (q = code quarter), wave tile 64 rows x 64 codes.
// LDS 81920 B: X[kb8][rf4][lane64][8]u16 @0 (32KB) ;
//              E stage @32768: wave q at +q*8192, parity buf 4KB each ;
//              en2 fp32[4096] @65536 (16KB).
__launch_bounds__(256, 2)
__global__ void dist12_kernel(const char* __restrict__ Xsw, const char* __restrict__ Esw,
                              const float* __restrict__ en2f, float4* __restrict__ top2) {
    __shared__ __align__(16) char lds[81920];
    const int tid  = threadIdx.x;
    const int lane = tid & 63;
    const int wid  = tid >> 6;          // 0..3 = code quarter q
    const int llo  = lane & 15, lhi = lane >> 4;
    const int rb = blockIdx.x;          // 0..511 (64-row group)

    const char* xb = Xsw + (size_t)rb * 32768;
    char* ldsE = lds + 32768 + wid * 8192;

    auto STAGE_E = [&](int p) {   // stage 4KB tile (ct=p>>3, q=wid, kb=p&7) into parity p&1
        const char* es = Esw + ((size_t)(((p >> 3) * 4 + wid) * 8 + (p & 7))) * 4096;
        char* lb = ldsE + (p & 1) * 4096;
        gload_lds16(es + lane * 16,        lb);
        gload_lds16(es + 1024 + lane * 16, lb + 1024);
        gload_lds16(es + 2048 + lane * 16, lb + 2048);
        gload_lds16(es + 3072 + lane * 16, lb + 3072);
    };

    unsigned pm0[16], pm1[16];          // packed (biased-val-bits & ~63) | (ct*4+j)
    #pragma unroll
    for (int s = 0; s < 16; ++s) { pm0[s] = 0xFFFFFFFFu; pm1[s] = 0xFFFFFFFFu; }

    f32x4 acc[4][4];
    #pragma unroll
    for (int i = 0; i < 4; ++i)
        #pragma unroll
        for (int j = 0; j < 4; ++j) acc[i][j] = (f32x4){0.f, 0.f, 0.f, 0.f};

    // prologue: X (32KB) + en2 table (16KB) to LDS, first E tile wave-private
    #pragma unroll
    for (int it = 0; it < 8; ++it)
        gload_lds16(xb + it * 4096 + tid * 16, lds + it * 4096 + wid * 1024);
    const char* en2c = reinterpret_cast<const char*>(en2f);
    #pragma unroll
    for (int it = 0; it < 4; ++it)
        gload_lds16(en2c + it * 4096 + tid * 16, lds + 65536 + it * 4096 + wid * 1024);
    STAGE_E(0);
    WAITVM(0);
    BARRIER();      // X + en2 visible to all waves; E tile 0 ready (wave-private)

    const f16x8* LX = reinterpret_cast<const f16x8*>(lds);
    const float* ENL = reinterpret_cast<const float*>(lds + 65536);

    for (int ct = 0; ct < 16; ++ct) {
        // biased en2 for this ctile (bias keeps v positive -> u32-monotonic packing;
        // per-row-constant bias does not change the argmin)
        float en[4];
        #pragma unroll
        for (int j = 0; j < 4; ++j)
            en[j] = ENL[ct * 256 + wid * 64 + j * 16 + llo] + 512.0f;

        #pragma unroll
        for (int kb = 0; kb < 8; ++kb) {
            const int p = ct * 8 + kb;
            if (p < 127) { STAGE_E(p + 1); WAITVM(4); }
            else         { WAITVM(0); }

            f16x8 ev[4];
            #pragma unroll
            for (int j = 0; j < 4; ++j)
                ev[j] = *reinterpret_cast<const f16x8*>(
                    ldsE + (p & 1) * 4096 + j * 1024 + lane * 16);

            __builtin_amdgcn_s_setprio(1);
            f16x8 av[4];
            #pragma unroll
            for (int i = 0; i < 4; ++i)
                av[i] = LX[(kb * 4 + i) * 64 + lane];
            #pragma unroll
            for (int i = 0; i < 4; ++i)
                #pragma unroll
                for (int j = 0; j < 4; ++j)
                    acc[i][j] = __builtin_amdgcn_mfma_f32_16x16x32_f16(
                        av[i], ev[j], acc[i][j], 0, 0, 0);
            __builtin_amdgcn_s_setprio(0);

            if (kb == 7) {
                // packed top-2 update: 6 VALU per candidate
                #pragma unroll
                for (int i = 0; i < 4; ++i) {
                    #pragma unroll
                    for (int r = 0; r < 4; ++r) {
                        const int s = i * 4 + r;
                        #pragma unroll
                        for (int j = 0; j < 4; ++j) {
                            const float v = en[j] + acc[i][j][r];
                            const unsigned c =
                                (__float_as_uint(v) & 0xFFFFFFC0u) | (unsigned)(ct * 4 + j);
                            const unsigned loser = pm0[s] > c ? pm0[s] : c;
                            pm0[s] = pm0[s] < c ? pm0[s] : c;
                            pm1[s] = pm1[s] < loser ? pm1[s] : loser;
                        }
                    }
                }
                #pragma unroll
                for (int i = 0; i < 4; ++i)
                    #pragma unroll
                    for (int j = 0; j < 4; ++j) acc[i][j] = (f32x4){0.f, 0.f, 0.f, 0.f};
            }
        }
    }

    // decode packed -> (biased val, global idx) once, then merge as before
    float tv0[16], tv1[16];
    int   tpk[16];
    #pragma unroll
    for (int s = 0; s < 16; ++s) {
        const unsigned a = pm0[s], b = pm1[s];
        const int t0 = (int)(a & 63u), t1 = (int)(b & 63u);
        tv0[s] = __uint_as_float(a & 0xFFFFFFC0u);
        tv1[s] = __uint_as_float(b & 0xFFFFFFC0u);
        const int g0 = (t0 >> 2) * 256 + wid * 64 + (t0 & 3) * 16 + llo;
        const int g1 = (t1 >> 2) * 256 + wid * 64 + (t1 & 3) * 16 + llo;
        tpk[s] = (g1 << 16) | g0;
    }

    // merge the 16 column-lanes (llo) via shfl butterfly
    #pragma unroll
    for (int m = 1; m <= 8; m <<= 1) {
        #pragma unroll
        for (int s = 0; s < 16; ++s) {
            float ov0 = __shfl_xor(tv0[s], m, 64);
            float ov1 = __shfl_xor(tv1[s], m, 64);
            int   opk = __shfl_xor(tpk[s], m, 64);
            float v0 = tv0[s], v1 = tv1[s];
            int i0 = tpk[s] & 0xffff, i1 = (tpk[s] >> 16) & 0xffff;
            top2_merge(v0, i0, v1, i1, ov0, opk & 0xffff, ov1, (opk >> 16) & 0xffff);
            tv0[s] = v0; tv1[s] = v1; tpk[s] = (i1 << 16) | i0;
        }
    }

    __syncthreads();
    float4* M = reinterpret_cast<float4*>(lds);   // [64 rows][4 q] (reuses X region)
    if (llo == 0) {
        #pragma unroll
        for (int i = 0; i < 4; ++i)
            #pragma unroll
            for (int r = 0; r < 4; ++r) {
                const int rowl = i * 16 + lhi * 4 + r;
                const int s = i * 4 + r;
                M[rowl * 4 + wid] = make_float4(tv0[s], __int_as_float(tpk[s] & 0xffff),
                                                tv1[s], __int_as_float((tpk[s] >> 16) & 0xffff));
            }
    }
    __syncthreads();
    if (tid < 64) {
        // pairwise merge: waves 0+1 -> entry 0, waves 2+3 -> entry 1
        #pragma unroll
        for (int h = 0; h < 2; ++h) {
            float4 A4 = M[tid * 4 + 2 * h], B4 = M[tid * 4 + 2 * h + 1];
            float v0 = A4.x, v1 = A4.z;
            int i0 = __float_as_int(A4.y), i1 = __float_as_int(A4.w);
            top2_merge(v0, i0, v1, i1, B4.x, __float_as_int(B4.y), B4.z, __float_as_int(B4.w));
            top2[(size_t)(rb * 64 + tid) * 2 + h] =
                make_float4(v0, __int_as_float(i0), v1, __int_as_float(i1));
        }
    }
}

// ---------- rescore: fp64 rescore of 4 candidates (2 per wave-pair) ----------
__global__ void rescore_kernel(const float* __restrict__ X, const float* __restrict__ E,
                               const float4* __restrict__ top2, float* __restrict__ out,
                               double* __restrict__ partials) {
    const int lane = threadIdx.x & 63;
    const int wid  = (blockIdx.x * blockDim.x + threadIdx.x) >> 6;
    const int nw   = (gridDim.x * blockDim.x) >> 6;
    double wloc = 0.0;

    for (int row = wid; row < B_N; row += nw) {
        float4 t0 = top2[(size_t)row * 2 + 0];
        float4 t1 = top2[(size_t)row * 2 + 1];
        int cand[4] = { __float_as_int(t0.y), __float_as_int(t0.w),
                        __float_as_int(t1.y), __float_as_int(t1.w) };
        const float4 xv = *reinterpret_cast<const float4*>(X + (size_t)row * D_N + lane * 4);

        double bestd = 1e300; int besti = 0x7fffffff;
        float4 beste = make_float4(0.f, 0.f, 0.f, 0.f);
        #pragma unroll
        for (int c = 0; c < 4; ++c) {
            const int k = cand[c];
            const float4 ev = *reinterpret_cast<const float4*>(E + (size_t)k * D_N + lane * 4);
            double dx = (double)xv.x - (double)ev.x;
            double dy = (double)xv.y - (double)ev.y;
            double dz = (double)xv.z - (double)ev.z;
            double dw = (double)xv.w - (double)ev.w;
            double s = dx * dx + dy * dy + dz * dz + dw * dw;
            #pragma unroll
            for (int o = 32; o; o >>= 1) s += __shfl_xor(s, o, 64);
            if (s < bestd || (s == bestd && k < besti)) { bestd = s; besti = k; beste = ev; }
        }
        *reinterpret_cast<float4*>(out + (size_t)row * D_N + lane * 4) = beste;
        wloc += bestd;
    }

    __shared__ double bsum[8];
    const int widx = threadIdx.x >> 6;
    if (lane == 0) bsum[widx] = wloc;
    __syncthreads();
    if (threadIdx.x == 0) {
        double s = 0.0;
        for (int w = 0; w < (int)(blockDim.x >> 6); ++w) s += bsum[w];
        partials[blockIdx.x] = s;
    }
}

__global__ void finalize_kernel(const double* __restrict__ partials, int n,
                                float* __restrict__ loss_out) {
    __shared__ double sm[256];
    double s = 0.0;
    for (int i = threadIdx.x; i < n; i += 256) s += partials[i];
    sm[threadIdx.x] = s;
    __syncthreads();
    for (int st = 128; st; st >>= 1) {
        if (threadIdx.x < st) sm[threadIdx.x] += sm[threadIdx.x + st];
        __syncthreads();
    }
    if (threadIdx.x == 0)
        *loss_out = (float)(1.25 * sm[0] / (double)((size_t)B_N * D_N));
}

extern "C" void kernel_launch(void* const* d_in, const int* in_sizes, int n_in,
                              void* d_out, int out_size, void* d_ws, size_t ws_size,
                              hipStream_t stream) {
    const float* X = (const float*)d_in[0];
    const float* E = (const float*)d_in[1];
    float* out = (float*)d_out;
    char* ws = (char*)d_ws;

    u16*    Xsw      = (u16*)d_out;          // 16 MiB scratch in d_out (overwritten by rescore)
    float4* top2     = (float4*)(ws + P_TOP2);
    u16*    Esw      = (u16*)(ws + P_ESW);
    float*  en2f     = (float*)(ws + P_EN2);
    double* partials = (double*)(ws + P_PART);

    xconv_kernel<<<(B_N * 32) / 256, 256, 0, stream>>>(X, Xsw);
    econv_kernel<<<(K_N * 32) / 256, 256, 0, stream>>>(E, Esw);
    en2_kernel<<<K_N / 4, 256, 0, stream>>>(E, en2f);
    dist12_kernel<<<B_N / 64, 256, 0, stream>>>(
        (const char*)Xsw, (const char*)Esw, en2f, top2);
    rescore_kernel<<<512, 256, 0, stream>>>(X, E, top2, out, partials);
    finalize_kernel<<<1, 256, 0, stream>>>(partials, 512, out + (size_t)B_N * D_N);
}

// Round 13
// 147.773 us; speedup vs baseline: 1.5567x; 1.0105x over previous
//
#include <hip/hip_runtime.h>

// VQ-VAE vector quantizer: B=32768, K=4096, D=256 (fp32)
// out = [quantized (B*D floats), vq_loss (1 float)]
//
//  xconv : X -> fp16 (hi only), 64-row-block frag tiles into d_out (16MB, overwritten later)
//  econv : E -> NEGATED fp16 (hi only), 8KB tiles per (ct,q,kbp): 64 codes x 64 k
//  en2   : en2r = 0.5*||e||^2 + 512 (bias prefolded), packed dwordx4 per (ct,q,llo)
//  dist13: barrier-free hi-only GEMM, 64 BIG phases (K=64 each, 32 MFMA).
//          X kb0-3 in 64 VGPRs (per-lane loads), X kb4-7 in LDS (16KB).
//          E staged wave-private via global_load_lds (8KB tiles, 2-parity dbuf,
//          counted vmcnt(8)/(9), no barriers). Packed-u32 top-2 epilogue per ctile.
//  rescore: fp64 rescore of 4 candidates -> exact winner, gather, loss partials
//  finalize: loss = 1.25 * mean((x-q)^2)

#define B_N 32768
#define K_N 4096
#define D_N 256

typedef _Float16 f16x8 __attribute__((ext_vector_type(8)));
typedef float f32x4 __attribute__((ext_vector_type(4)));
typedef unsigned int uint4v __attribute__((ext_vector_type(4)));
typedef unsigned short u16;

// ws layout (~3.1 MB)
static constexpr size_t P_TOP2 = 0;                               // 32768*2*16 = 1 MB
static constexpr size_t P_ESW  = (size_t)B_N * 2 * 16;            // +2 MB
static constexpr size_t P_EN2  = P_ESW + (size_t)K_N * D_N * 2;   // +16 KB
static constexpr size_t P_PART = P_EN2 + (size_t)K_N * 4;         // +4 KB

__device__ __forceinline__ u16 f2h(float f) {
    _Float16 h = (_Float16)f;
    return __builtin_bit_cast(u16, h);
}

__device__ __forceinline__ void gload_lds16(const void* g, void* l) {
    __builtin_amdgcn_global_load_lds(
        (const __attribute__((address_space(1))) void*)g,
        (__attribute__((address_space(3))) void*)l, 16, 0, 0);
}

#define WAITVM(N) asm volatile("s_waitcnt vmcnt(" #N ")" ::: "memory")
#define BARRIER() __builtin_amdgcn_s_barrier()

__device__ __forceinline__ void top2_merge(float& v0, int& i0, float& v1, int& i1,
                                           float ov0, int oi0, float ov1, int oi1) {
    bool bf_ = (ov0 < v0) || (ov0 == v0 && oi0 < i0);
    float w0v = bf_ ? ov0 : v0;  int w0i = bf_ ? oi0 : i0;
    float lv  = bf_ ? v0  : ov0; int li  = bf_ ? i0  : oi0;
    float cv  = bf_ ? ov1 : v1;  int ci  = bf_ ? oi1 : i1;
    bool tl = (lv < cv) || (lv == cv && li < ci);
    v0 = w0v; i0 = w0i;
    v1 = tl ? lv : cv; i1 = tl ? li : ci;
}

// ---------- xconv: X -> fp16 hi, 64-row-block tiles ----------
// u16 index = rb*16384 + kb*2048 + rf*512 + lane*8
// row = rb*64 + rf*16 + llo ; d = kb*32 + lhi*8 + j ; lane = lhi*16+llo
__global__ void xconv_kernel(const float* __restrict__ X, u16* __restrict__ Xsw) {
    const int gid = blockIdx.x * 256 + threadIdx.x;     // B_N*32 threads
    const int row = gid >> 5;
    const int d0  = (gid & 31) << 3;
    const float4 a = *reinterpret_cast<const float4*>(X + (size_t)row * D_N + d0);
    const float4 b = *reinterpret_cast<const float4*>(X + (size_t)row * D_N + d0 + 4);
    float f[8] = {a.x, a.y, a.z, a.w, b.x, b.y, b.z, b.w};
    unsigned hi[8];
    #pragma unroll
    for (int j = 0; j < 8; ++j) hi[j] = f2h(f[j]);
    const int rb = row >> 6, rr = row & 63, rf = rr >> 4, llo = rr & 15;
    const int kb = d0 >> 5, lhi = (d0 & 31) >> 3, lane = lhi * 16 + llo;
    size_t base = (size_t)rb * 16384 + (size_t)kb * 2048 + (size_t)rf * 512 + (size_t)lane * 8;
    uint4v hv;
    hv.x = hi[0] | (hi[1] << 16); hv.y = hi[2] | (hi[3] << 16);
    hv.z = hi[4] | (hi[5] << 16); hv.w = hi[6] | (hi[7] << 16);
    *reinterpret_cast<uint4v*>(Xsw + base) = hv;
}

// ---------- econv: E -> negated fp16 hi, 8KB tiles (ct,q,kbp) ----------
// code = ct*256 + q*64 + j*16 + llo ; kb = d0>>5, kbp = kb>>1, kk = kb&1
// u16 index = ((ct*4+q)*4 + kbp)*4096 + (kk*4+j)*512 + lane*8
__global__ void econv_kernel(const float* __restrict__ E, u16* __restrict__ Esw) {
    const int gid = blockIdx.x * 256 + threadIdx.x;     // K_N*32 threads
    const int code = gid >> 5;
    const int d0  = (gid & 31) << 3;
    const float4 a = *reinterpret_cast<const float4*>(E + (size_t)code * D_N + d0);
    const float4 b = *reinterpret_cast<const float4*>(E + (size_t)code * D_N + d0 + 4);
    float f[8] = {a.x, a.y, a.z, a.w, b.x, b.y, b.z, b.w};
    unsigned hi[8];
    #pragma unroll
    for (int j = 0; j < 8; ++j) hi[j] = f2h(-f[j]);
    const int ct = code >> 8, q = (code >> 6) & 3, cf = (code >> 4) & 3, llo = code & 15;
    const int kb = d0 >> 5, kbp = kb >> 1, kk = kb & 1;
    const int lhi = (d0 & 31) >> 3, lane = lhi * 16 + llo;
    size_t base = ((size_t)((ct * 4 + q) * 4 + kbp)) * 4096
                + (size_t)(kk * 4 + cf) * 512 + (size_t)lane * 8;
    uint4v hv;
    hv.x = hi[0] | (hi[1] << 16); hv.y = hi[2] | (hi[3] << 16);
    hv.z = hi[4] | (hi[5] << 16); hv.w = hi[6] | (hi[7] << 16);
    *reinterpret_cast<uint4v*>(Esw + base) = hv;
}

// ---------- en2: 0.5||e||^2 + 512, repacked for dwordx4 per-lane loads ----------
// en2r[((ct*4+q)*16 + llo)*4 + j] ; code = ct*256 + q*64 + j*16 + llo
__global__ void en2_kernel(const float* __restrict__ E, float* __restrict__ en2r) {
    const int gtid = blockIdx.x * blockDim.x + threadIdx.x;
    const int code = gtid >> 6;
    const int lane = threadIdx.x & 63;
    if (code >= K_N) return;
    const float4 v = *reinterpret_cast<const float4*>(E + (size_t)code * D_N + lane * 4);
    double s = (double)v.x * v.x + (double)v.y * v.y + (double)v.z * v.z + (double)v.w * v.w;
    #pragma unroll
    for (int o = 32; o; o >>= 1) s += __shfl_xor(s, o, 64);
    if (lane == 0) {
        const int ct = code >> 8, q = (code >> 6) & 3, j = (code >> 4) & 3, llo = code & 15;
        en2r[(size_t)(((ct * 4 + q) * 16 + llo) * 4 + j)] = (float)(0.5 * s) + 512.0f;
    }
}

// ---------- dist13: 64 big phases (K=64), X half-in-regs, packed-u32 top-2 ----------
// 512 blocks, 256 thr = 4 waves (q = code quarter), wave tile 64 rows x 64 codes.
// LDS 81920 B: X kb4-7 @0 (16KB) ; E stage @16384: wave q at +q*16384, parity 8KB.
__launch_bounds__(256, 2)
__global__ void dist13_kernel(const char* __restrict__ Xsw, const char* __restrict__ Esw,
                              const float* __restrict__ en2r, float4* __restrict__ top2) {
    __shared__ __align__(16) char lds[81920];
    const int tid  = threadIdx.x;
    const int lane = tid & 63;
    const int wid  = tid >> 6;          // 0..3 = code quarter q
    const int llo  = lane & 15, lhi = lane >> 4;
    const int rb = blockIdx.x;          // 0..511 (64-row group)

    const char* xb = Xsw + (size_t)rb * 32768;
    char* ldsE = lds + 16384 + wid * 16384;

    auto STAGE_E = [&](int p) {   // stage 8KB tile (ct=p>>2, q=wid, kbp=p&3) into parity p&1
        const char* es = Esw + ((size_t)(((p >> 2) * 4 + wid) * 4 + (p & 3))) * 8192;
        char* lb = ldsE + (p & 1) * 8192;
        #pragma unroll
        for (int it = 0; it < 8; ++it)
            gload_lds16(es + it * 1024 + lane * 16, lb + it * 1024);
    };

    unsigned pm0[16], pm1[16];          // packed (biased-val-bits & ~63) | (ct*4+j)
    #pragma unroll
    for (int s = 0; s < 16; ++s) { pm0[s] = 0xFFFFFFFFu; pm1[s] = 0xFFFFFFFFu; }

    f32x4 acc[4][4];
    #pragma unroll
    for (int i = 0; i < 4; ++i)
        #pragma unroll
        for (int j = 0; j < 4; ++j) acc[i][j] = (f32x4){0.f, 0.f, 0.f, 0.f};

    // prologue: X kb0-3 -> 64 VGPRs (per-lane), X kb4-7 -> LDS, E tile 0, en2(ct0)
    f16x8 xr[4][4];
    #pragma unroll
    for (int kb = 0; kb < 4; ++kb)
        #pragma unroll
        for (int i = 0; i < 4; ++i)
            xr[kb][i] = *reinterpret_cast<const f16x8*>(
                xb + (size_t)(kb * 4 + i) * 1024 + (size_t)lane * 16);
    #pragma unroll
    for (int it = 0; it < 4; ++it)
        gload_lds16(xb + 16384 + it * 4096 + tid * 16, lds + it * 4096 + wid * 1024);
    STAGE_E(0);
    const float* enp = en2r + (size_t)(wid * 16 + llo) * 4;   // + ct*256
    float4 ena = *reinterpret_cast<const float4*>(enp);
    float4 enb;
    WAITVM(0);
    BARRIER();      // X-LDS visible to all waves (only needed intra-wave, but cheap)

    const f16x8* LX = reinterpret_cast<const f16x8*>(lds);

    #pragma unroll 1
    for (int ct = 0; ct < 16; ++ct) {
        #pragma unroll
        for (int kbp = 0; kbp < 4; ++kbp) {
            const int p = ct * 4 + kbp;
            bool en_issued = false;
            if (p < 63) STAGE_E(p + 1);
            if (kbp == 0 && ct < 15) {
                enb = *reinterpret_cast<const float4*>(enp + (ct + 1) * 256);
                en_issued = true;
            }
            if (p == 63)        { WAITVM(0); }
            else if (en_issued) { WAITVM(9); }
            else                { WAITVM(8); }

            f16x8 ev[8];
            #pragma unroll
            for (int u = 0; u < 8; ++u)
                ev[u] = *reinterpret_cast<const f16x8*>(
                    ldsE + (p & 1) * 8192 + u * 1024 + lane * 16);

            __builtin_amdgcn_s_setprio(1);
            #pragma unroll
            for (int kk = 0; kk < 2; ++kk) {
                f16x8 av[4];
                if (kbp < 2) {
                    #pragma unroll
                    for (int i = 0; i < 4; ++i) av[i] = xr[kbp * 2 + kk][i];
                } else {
                    #pragma unroll
                    for (int i = 0; i < 4; ++i)
                        av[i] = LX[(((kbp - 2) * 2 + kk) * 4 + i) * 64 + lane];
                }
                #pragma unroll
                for (int i = 0; i < 4; ++i)
                    #pragma unroll
                    for (int j = 0; j < 4; ++j)
                        acc[i][j] = __builtin_amdgcn_mfma_f32_16x16x32_f16(
                            av[i], ev[kk * 4 + j], acc[i][j], 0, 0, 0);
            }
            __builtin_amdgcn_s_setprio(0);

            if (kbp == 3) {
                // packed top-2 update: 6 VALU per candidate
                const float en4[4] = {ena.x, ena.y, ena.z, ena.w};
                #pragma unroll
                for (int i = 0; i < 4; ++i) {
                    #pragma unroll
                    for (int r = 0; r < 4; ++r) {
                        const int s = i * 4 + r;
                        #pragma unroll
                        for (int j = 0; j < 4; ++j) {
                            const float v = en4[j] + acc[i][j][r];
                            const unsigned c =
                                (__float_as_uint(v) & 0xFFFFFFC0u) | (unsigned)(ct * 4 + j);
                            const unsigned loser = pm0[s] > c ? pm0[s] : c;
                            pm0[s] = pm0[s] < c ? pm0[s] : c;
                            pm1[s] = pm1[s] < loser ? pm1[s] : loser;
                        }
                    }
                }
                #pragma unroll
                for (int i = 0; i < 4; ++i)
                    #pragma unroll
                    for (int j = 0; j < 4; ++j) acc[i][j] = (f32x4){0.f, 0.f, 0.f, 0.f};
                ena = enb;
            }
        }
    }

    // decode packed -> (biased val, global idx) once, then merge as before
    float tv0[16], tv1[16];
    int   tpk[16];
    #pragma unroll
    for (int s = 0; s < 16; ++s) {
        const unsigned a = pm0[s], b = pm1[s];
        const int t0 = (int)(a & 63u), t1 = (int)(b & 63u);
        tv0[s] = __uint_as_float(a & 0xFFFFFFC0u);
        tv1[s] = __uint_as_float(b & 0xFFFFFFC0u);
        const int g0 = (t0 >> 2) * 256 + wid * 64 + (t0 & 3) * 16 + llo;
        const int g1 = (t1 >> 2) * 256 + wid * 64 + (t1 & 3) * 16 + llo;
        tpk[s] = (g1 << 16) | g0;
    }

    // merge the 16 column-lanes (llo) via shfl butterfly
    #pragma unroll
    for (int m = 1; m <= 8; m <<= 1) {
        #pragma unroll
        for (int s = 0; s < 16; ++s) {
            float ov0 = __shfl_xor(tv0[s], m, 64);
            float ov1 = __shfl_xor(tv1[s], m, 64);
            int   opk = __shfl_xor(tpk[s], m, 64);
            float v0 = tv0[s], v1 = tv1[s];
            int i0 = tpk[s] & 0xffff, i1 = (tpk[s] >> 16) & 0xffff;
            top2_merge(v0, i0, v1, i1, ov0, opk & 0xffff, ov1, (opk >> 16) & 0xffff);
            tv0[s] = v0; tv1[s] = v1; tpk[s] = (i1 << 16) | i0;
        }
    }

    __syncthreads();
    float4* M = reinterpret_cast<float4*>(lds);   // [64 rows][4 q] (reuses X region)
    if (llo == 0) {
        #pragma unroll
        for (int i = 0; i < 4; ++i)
            #pragma unroll
            for (int r = 0; r < 4; ++r) {
                const int rowl = i * 16 + lhi * 4 + r;
                const int s = i * 4 + r;
                M[rowl * 4 + wid] = make_float4(tv0[s], __int_as_float(tpk[s] & 0xffff),
                                                tv1[s], __int_as_float((tpk[s] >> 16) & 0xffff));
            }
    }
    __syncthreads();
    if (tid < 64) {
        // pairwise merge: waves 0+1 -> entry 0, waves 2+3 -> entry 1
        #pragma unroll
        for (int h = 0; h < 2; ++h) {
            float4 A4 = M[tid * 4 + 2 * h], B4 = M[tid * 4 + 2 * h + 1];
            float v0 = A4.x, v1 = A4.z;
            int i0 = __float_as_int(A4.y), i1 = __float_as_int(A4.w);
            top2_merge(v0, i0, v1, i1, B4.x, __float_as_int(B4.y), B4.z, __float_as_int(B4.w));
            top2[(size_t)(rb * 64 + tid) * 2 + h] =
                make_float4(v0, __int_as_float(i0), v1, __int_as_float(i1));
        }
    }
}

// ---------- rescore: fp64 rescore of 4 candidates (2 per wave-pair) ----------
__global__ void rescore_kernel(const float* __restrict__ X, const float* __restrict__ E,
                               const float4* __restrict__ top2, float* __restrict__ out,
                               double* __restrict__ partials) {
    const int lane = threadIdx.x & 63;
    const int wid  = (blockIdx.x * blockDim.x + threadIdx.x) >> 6;
    const int nw   = (gridDim.x * blockDim.x) >> 6;
    double wloc = 0.0;

    for (int row = wid; row < B_N; row += nw) {
        float4 t0 = top2[(size_t)row * 2 + 0];
        float4 t1 = top2[(size_t)row * 2 + 1];
        int cand[4] = { __float_as_int(t0.y), __float_as_int(t0.w),
                        __float_as_int(t1.y), __float_as_int(t1.w) };
        const float4 xv = *reinterpret_cast<const float4*>(X + (size_t)row * D_N + lane * 4);

        double bestd = 1e300; int besti = 0x7fffffff;
        float4 beste = make_float4(0.f, 0.f, 0.f, 0.f);
        #pragma unroll
        for (int c = 0; c < 4; ++c) {
            const int k = cand[c];
            const float4 ev = *reinterpret_cast<const float4*>(E + (size_t)k * D_N + lane * 4);
            double dx = (double)xv.x - (double)ev.x;
            double dy = (double)xv.y - (double)ev.y;
            double dz = (double)xv.z - (double)ev.z;
            double dw = (double)xv.w - (double)ev.w;
            double s = dx * dx + dy * dy + dz * dz + dw * dw;
            #pragma unroll
            for (int o = 32; o; o >>= 1) s += __shfl_xor(s, o, 64);
            if (s < bestd || (s == bestd && k < besti)) { bestd = s; besti = k; beste = ev; }
        }
        *reinterpret_cast<float4*>(out + (size_t)row * D_N + lane * 4) = beste;
        wloc += bestd;
    }

    __shared__ double bsum[8];
    const int widx = threadIdx.x >> 6;
    if (lane == 0) bsum[widx] = wloc;
    __syncthreads();
    if (threadIdx.x == 0) {
        double s = 0.0;
        for (int w = 0; w < (int)(blockDim.x >> 6); ++w) s += bsum[w];
        partials[blockIdx.x] = s;
    }
}

__global__ void finalize_kernel(const double* __restrict__ partials, int n,
                                float* __restrict__ loss_out) {
    __shared__ double sm[256];
    double s = 0.0;
    for (int i = threadIdx.x; i < n; i += 256) s += partials[i];
    sm[threadIdx.x] = s;
    __syncthreads();
    for (int st = 128; st; st >>= 1) {
        if (threadIdx.x < st) sm[threadIdx.x] += sm[threadIdx.x + st];
        __syncthreads();
    }
    if (threadIdx.x == 0)
        *loss_out = (float)(1.25 * sm[0] / (double)((size_t)B_N * D_N));
}

extern "C" void kernel_launch(void* const* d_in, const int* in_sizes, int n_in,
                              void* d_out, int out_size, void* d_ws, size_t ws_size,
                              hipStream_t stream) {
    const float* X = (const float*)d_in[0];
    const float* E = (const float*)d_in[1];
    float* out = (float*)d_out;
    char* ws = (char*)d_ws;

    u16*    Xsw      = (u16*)d_out;          // 16 MiB scratch in d_out (overwritten by rescore)
    float4* top2     = (float4*)(ws + P_TOP2);
    u16*    Esw      = (u16*)(ws + P_ESW);
    float*  en2r     = (float*)(ws + P_EN2);
    double* partials = (double*)(ws + P_PART);

    xconv_kernel<<<(B_N * 32) / 256, 256, 0, stream>>>(X, Xsw);
    econv_kernel<<<(K_N * 32) / 256, 256, 0, stream>>>(E, Esw);
    en2_kernel<<<K_N / 4, 256, 0, stream>>>(E, en2r);
    dist13_kernel<<<B_N / 64, 256, 0, stream>>>(
        (const char*)Xsw, (const char*)Esw, en2r, top2);
    rescore_kernel<<<512, 256, 0, stream>>>(X, E, top2, out, partials);
    finalize_kernel<<<1, 256, 0, stream>>>(partials, 512, out + (size_t)B_N * D_N);
}

// Round 14
// 141.000 us; speedup vs baseline: 1.6314x; 1.0480x over previous
//
#include <hip/hip_runtime.h>

// VQ-VAE vector quantizer: B=32768, K=4096, D=256 (fp32)
// out = [quantized (B*D floats), vq_loss (1 float)]
//
//  econv_en2: E -> NEGATED fp16 (hi only) frag tiles in ws (16KB per (ct,kb)),
//             fused en2r[k] = 0.5||e||^2 + 512 (bias prefolded), repacked float4
//  dist14 : barrier-free hi-only GEMM, 1024 blocks x 32 rows. X fp32 -> fp16
//           converted IN-PROLOGUE into 16KB LDS (read-only). E streamed
//           global->register (parity-alternating bv dbuf, compiler-counted
//           vmcnt, R8 pattern). 4 waves = 4 code quarters, wave 32r x 64c,
//           128 phases (16 ct x 8 kb) x 8 MFMA. Packed-u32 top-2 per ctile.
//  rescore: fp64 rescore of 4 candidates -> exact winner, gather, loss partials
//  finalize: loss = 1.25 * mean((x-q)^2)

#define B_N 32768
#define K_N 4096
#define D_N 256

typedef _Float16 f16x8 __attribute__((ext_vector_type(8)));
typedef float f32x4 __attribute__((ext_vector_type(4)));
typedef unsigned int uint4v __attribute__((ext_vector_type(4)));
typedef unsigned short u16;

// ws layout (~3.1 MB)
static constexpr size_t P_TOP2 = 0;                               // 32768*2*16 = 1 MB
static constexpr size_t P_ESW  = (size_t)B_N * 2 * 16;            // +2 MB
static constexpr size_t P_EN2  = P_ESW + (size_t)K_N * D_N * 2;   // +16 KB
static constexpr size_t P_PART = P_EN2 + (size_t)K_N * 4;         // +4 KB

__device__ __forceinline__ u16 f2h(float f) {
    _Float16 h = (_Float16)f;
    return __builtin_bit_cast(u16, h);
}

#define BARRIER() __builtin_amdgcn_s_barrier()

__device__ __forceinline__ void top2_merge(float& v0, int& i0, float& v1, int& i1,
                                           float ov0, int oi0, float ov1, int oi1) {
    bool bf_ = (ov0 < v0) || (ov0 == v0 && oi0 < i0);
    float w0v = bf_ ? ov0 : v0;  int w0i = bf_ ? oi0 : i0;
    float lv  = bf_ ? v0  : ov0; int li  = bf_ ? i0  : oi0;
    float cv  = bf_ ? ov1 : v1;  int ci  = bf_ ? oi1 : i1;
    bool tl = (lv < cv) || (lv == cv && li < ci);
    v0 = w0v; i0 = w0i;
    v1 = tl ? lv : cv; i1 = tl ? li : ci;
}

// ---------- econv_en2: E -> negated fp16 hi frags + fused 0.5||e||^2+512 ----------
// code = ct*256 + wc*64 + j*16 + llo ; d = kb*32 + lhi*8 + jj
// Esw u16 idx = (ct*8+kb)*8192 + wc*2048 + j*512 + (lhi*16+llo)*8
// en2r f32 idx = ((ct*4+wc)*16 + llo)*4 + j
__global__ void econv_en2_kernel(const float* __restrict__ E, u16* __restrict__ Esw,
                                 float* __restrict__ en2r) {
    const int gid = blockIdx.x * 256 + threadIdx.x;     // K_N*32 threads
    const int code = gid >> 5;
    const int d0  = (gid & 31) << 3;
    const float4 a = *reinterpret_cast<const float4*>(E + (size_t)code * D_N + d0);
    const float4 b = *reinterpret_cast<const float4*>(E + (size_t)code * D_N + d0 + 4);
    float f[8] = {a.x, a.y, a.z, a.w, b.x, b.y, b.z, b.w};
    unsigned hi[8];
    double ss = 0.0;
    #pragma unroll
    for (int j = 0; j < 8; ++j) {
        hi[j] = f2h(-f[j]);
        ss += (double)f[j] * f[j];
    }
    const int ct = code >> 8, wc = (code >> 6) & 3, j = (code >> 4) & 3, llo = code & 15;
    const int kb = d0 >> 5, lhi = (d0 & 31) >> 3, lane = lhi * 16 + llo;
    size_t base = (size_t)(ct * 8 + kb) * 8192 + (size_t)wc * 2048
                + (size_t)j * 512 + (size_t)lane * 8;
    uint4v hv;
    hv.x = hi[0] | (hi[1] << 16); hv.y = hi[2] | (hi[3] << 16);
    hv.z = hi[4] | (hi[5] << 16); hv.w = hi[6] | (hi[7] << 16);
    *reinterpret_cast<uint4v*>(Esw + base) = hv;
    // reduce ||e||^2 over the 32 threads of this code (stay within 32-lane half)
    #pragma unroll
    for (int o = 16; o; o >>= 1) ss += __shfl_xor(ss, o, 64);
    if ((gid & 31) == 0)
        en2r[(size_t)(((ct * 4 + wc) * 16 + llo) * 4 + j)] = (float)(0.5 * ss) + 512.0f;
}

// ---------- dist14: 32-row blocks, X converted in-prologue, E reg-streamed ----------
// 1024 blocks, 256 thr = 4 waves (wc = code quarter), wave tile 32 rows x 64 codes.
// LDS 16384 B: X fp16 [kb8][rf2][lane64][8]u16 (read-only after prologue barrier).
__launch_bounds__(256, 2)
__global__ void dist14_kernel(const float* __restrict__ X, const char* __restrict__ Esw,
                              const float* __restrict__ en2r, float4* __restrict__ top2) {
    __shared__ __align__(16) char lds[16384];
    const int tid  = threadIdx.x;
    const int lane = tid & 63;
    const int wid  = tid >> 6;          // 0..3 = code quarter wc
    const int llo  = lane & 15, lhi = lane >> 4;
    const int rb = blockIdx.x;          // 0..1023 (32-row group)

    // per-wave E fragment base: phase p = ct*8+kb, frag j at ep + p*16384 + j*1024
    const char* ep = Esw + (size_t)wid * 4096 + (size_t)lane * 16;
    const float* enp = en2r + (size_t)(wid * 16 + llo) * 4;   // + ct*256

    unsigned pm0[8], pm1[8];            // packed (biased-val-bits & ~63) | (ct*4+j)
    #pragma unroll
    for (int s = 0; s < 8; ++s) { pm0[s] = 0xFFFFFFFFu; pm1[s] = 0xFFFFFFFFu; }

    f32x4 acc[2][4];
    #pragma unroll
    for (int i = 0; i < 2; ++i)
        #pragma unroll
        for (int j = 0; j < 4; ++j) acc[i][j] = (f32x4){0.f, 0.f, 0.f, 0.f};

    // prologue: convert X fp32 -> fp16 frag layout in LDS (32 rows x 256 d)
    const float* xb = X + (size_t)rb * 32 * D_N;
    #pragma unroll
    for (int u = 0; u < 4; ++u) {
        const int job = u * 256 + tid;          // 0..1023
        const int row = job >> 5;               // 0..31
        const int d0  = (job & 31) << 3;
        const float4 a = *reinterpret_cast<const float4*>(xb + (size_t)row * D_N + d0);
        const float4 b = *reinterpret_cast<const float4*>(xb + (size_t)row * D_N + d0 + 4);
        float f[8] = {a.x, a.y, a.z, a.w, b.x, b.y, b.z, b.w};
        unsigned hv[4];
        #pragma unroll
        for (int j = 0; j < 4; ++j)
            hv[j] = f2h(f[2 * j]) | ((unsigned)f2h(f[2 * j + 1]) << 16);
        const int kb = d0 >> 5, lh2 = (d0 & 31) >> 3, rf = row >> 4;
        const int lane2 = lh2 * 16 + (row & 15);
        uint4v* dst = reinterpret_cast<uint4v*>(
            lds + (size_t)((kb * 2 + rf) * 64 + lane2) * 16);
        uint4v w; w.x = hv[0]; w.y = hv[1]; w.z = hv[2]; w.w = hv[3];
        *dst = w;
    }
    // first E phase into parity 0
    f16x8 bv[2][4];
    #pragma unroll
    for (int j = 0; j < 4; ++j)
        bv[0][j] = *reinterpret_cast<const f16x8*>(ep + j * 1024);
    __syncthreads();    // X-LDS visible to all waves (ds_write drain + barrier)

    const f16x8* LX = reinterpret_cast<const f16x8*>(lds);

    #pragma unroll 1
    for (int ct = 0; ct < 16; ++ct) {
        const float4 ena = *reinterpret_cast<const float4*>(enp + ct * 256);
        #pragma unroll
        for (int kb = 0; kb < 8; ++kb) {
            const int p = ct * 8 + kb;
            // prefetch phase p+1 E frags into the other parity buffer
            if (p < 127) {
                #pragma unroll
                for (int j = 0; j < 4; ++j)
                    bv[(kb + 1) & 1][j] = *reinterpret_cast<const f16x8*>(
                        ep + (size_t)(p + 1) * 16384 + j * 1024);
            }

            __builtin_amdgcn_s_setprio(1);
            f16x8 av[2];
            #pragma unroll
            for (int i = 0; i < 2; ++i)
                av[i] = LX[(kb * 2 + i) * 64 + lane];
            #pragma unroll
            for (int i = 0; i < 2; ++i)
                #pragma unroll
                for (int j = 0; j < 4; ++j)
                    acc[i][j] = __builtin_amdgcn_mfma_f32_16x16x32_f16(
                        av[i], bv[kb & 1][j], acc[i][j], 0, 0, 0);
            __builtin_amdgcn_s_setprio(0);

            if (kb == 7) {
                // packed top-2 update: 6 VALU per candidate
                const float en4[4] = {ena.x, ena.y, ena.z, ena.w};
                #pragma unroll
                for (int i = 0; i < 2; ++i) {
                    #pragma unroll
                    for (int r = 0; r < 4; ++r) {
                        const int s = i * 4 + r;
                        #pragma unroll
                        for (int j = 0; j < 4; ++j) {
                            const float v = en4[j] + acc[i][j][r];
                            const unsigned c =
                                (__float_as_uint(v) & 0xFFFFFFC0u) | (unsigned)(ct * 4 + j);
                            const unsigned loser = pm0[s] > c ? pm0[s] : c;
                            pm0[s] = pm0[s] < c ? pm0[s] : c;
                            pm1[s] = pm1[s] < loser ? pm1[s] : loser;
                        }
                    }
                }
                #pragma unroll
                for (int i = 0; i < 2; ++i)
                    #pragma unroll
                    for (int j = 0; j < 4; ++j) acc[i][j] = (f32x4){0.f, 0.f, 0.f, 0.f};
            }
        }
    }

    // decode packed -> (biased val, global idx)
    float tv0[8], tv1[8];
    int   tpk[8];
    #pragma unroll
    for (int s = 0; s < 8; ++s) {
        const unsigned a = pm0[s], b = pm1[s];
        const int t0 = (int)(a & 63u), t1 = (int)(b & 63u);
        tv0[s] = __uint_as_float(a & 0xFFFFFFC0u);
        tv1[s] = __uint_as_float(b & 0xFFFFFFC0u);
        const int g0 = (t0 >> 2) * 256 + wid * 64 + (t0 & 3) * 16 + llo;
        const int g1 = (t1 >> 2) * 256 + wid * 64 + (t1 & 3) * 16 + llo;
        tpk[s] = (g1 << 16) | g0;
    }

    // merge the 16 column-lanes (llo) via shfl butterfly
    #pragma unroll
    for (int m = 1; m <= 8; m <<= 1) {
        #pragma unroll
        for (int s = 0; s < 8; ++s) {
            float ov0 = __shfl_xor(tv0[s], m, 64);
            float ov1 = __shfl_xor(tv1[s], m, 64);
            int   opk = __shfl_xor(tpk[s], m, 64);
            float v0 = tv0[s], v1 = tv1[s];
            int i0 = tpk[s] & 0xffff, i1 = (tpk[s] >> 16) & 0xffff;
            top2_merge(v0, i0, v1, i1, ov0, opk & 0xffff, ov1, (opk >> 16) & 0xffff);
            tv0[s] = v0; tv1[s] = v1; tpk[s] = (i1 << 16) | i0;
        }
    }

    __syncthreads();
    float4* M = reinterpret_cast<float4*>(lds);   // [32 rows][4 wc] (reuses X region)
    if (llo == 0) {
        #pragma unroll
        for (int i = 0; i < 2; ++i)
            #pragma unroll
            for (int r = 0; r < 4; ++r) {
                const int rowl = i * 16 + lhi * 4 + r;
                const int s = i * 4 + r;
                M[rowl * 4 + wid] = make_float4(tv0[s], __int_as_float(tpk[s] & 0xffff),
                                                tv1[s], __int_as_float((tpk[s] >> 16) & 0xffff));
            }
    }
    __syncthreads();
    if (tid < 32) {
        // pairwise merge: waves 0+1 -> entry 0, waves 2+3 -> entry 1
        #pragma unroll
        for (int h = 0; h < 2; ++h) {
            float4 A4 = M[tid * 4 + 2 * h], B4 = M[tid * 4 + 2 * h + 1];
            float v0 = A4.x, v1 = A4.z;
            int i0 = __float_as_int(A4.y), i1 = __float_as_int(A4.w);
            top2_merge(v0, i0, v1, i1, B4.x, __float_as_int(B4.y), B4.z, __float_as_int(B4.w));
            top2[(size_t)(rb * 32 + tid) * 2 + h] =
                make_float4(v0, __int_as_float(i0), v1, __int_as_float(i1));
        }
    }
}

// ---------- rescore: fp64 rescore of 4 candidates (2 per wave-pair) ----------
__global__ void rescore_kernel(const float* __restrict__ X, const float* __restrict__ E,
                               const float4* __restrict__ top2, float* __restrict__ out,
                               double* __restrict__ partials) {
    const int lane = threadIdx.x & 63;
    const int wid  = (blockIdx.x * blockDim.x + threadIdx.x) >> 6;
    const int nw   = (gridDim.x * blockDim.x) >> 6;
    double wloc = 0.0;

    for (int row = wid; row < B_N; row += nw) {
        float4 t0 = top2[(size_t)row * 2 + 0];
        float4 t1 = top2[(size_t)row * 2 + 1];
        int cand[4] = { __float_as_int(t0.y), __float_as_int(t0.w),
                        __float_as_int(t1.y), __float_as_int(t1.w) };
        const float4 xv = *reinterpret_cast<const float4*>(X + (size_t)row * D_N + lane * 4);

        double bestd = 1e300; int besti = 0x7fffffff;
        float4 beste = make_float4(0.f, 0.f, 0.f, 0.f);
        #pragma unroll
        for (int c = 0; c < 4; ++c) {
            const int k = cand[c];
            const float4 ev = *reinterpret_cast<const float4*>(E + (size_t)k * D_N + lane * 4);
            double dx = (double)xv.x - (double)ev.x;
            double dy = (double)xv.y - (double)ev.y;
            double dz = (double)xv.z - (double)ev.z;
            double dw = (double)xv.w - (double)ev.w;
            double s = dx * dx + dy * dy + dz * dz + dw * dw;
            #pragma unroll
            for (int o = 32; o; o >>= 1) s += __shfl_xor(s, o, 64);
            if (s < bestd || (s == bestd && k < besti)) { bestd = s; besti = k; beste = ev; }
        }
        *reinterpret_cast<float4*>(out + (size_t)row * D_N + lane * 4) = beste;
        wloc += bestd;
    }

    __shared__ double bsum[8];
    const int widx = threadIdx.x >> 6;
    if (lane == 0) bsum[widx] = wloc;
    __syncthreads();
    if (threadIdx.x == 0) {
        double s = 0.0;
        for (int w = 0; w < (int)(blockDim.x >> 6); ++w) s += bsum[w];
        partials[blockIdx.x] = s;
    }
}

__global__ void finalize_kernel(const double* __restrict__ partials, int n,
                                float* __restrict__ loss_out) {
    __shared__ double sm[256];
    double s = 0.0;
    for (int i = threadIdx.x; i < n; i += 256) s += partials[i];
    sm[threadIdx.x] = s;
    __syncthreads();
    for (int st = 128; st; st >>= 1) {
        if (threadIdx.x < st) sm[threadIdx.x] += sm[threadIdx.x + st];
        __syncthreads();
    }
    if (threadIdx.x == 0)
        *loss_out = (float)(1.25 * sm[0] / (double)((size_t)B_N * D_N));
}

extern "C" void kernel_launch(void* const* d_in, const int* in_sizes, int n_in,
                              void* d_out, int out_size, void* d_ws, size_t ws_size,
                              hipStream_t stream) {
    const float* X = (const float*)d_in[0];
    const float* E = (const float*)d_in[1];
    float* out = (float*)d_out;
    char* ws = (char*)d_ws;

    float4* top2     = (float4*)(ws + P_TOP2);
    u16*    Esw      = (u16*)(ws + P_ESW);
    float*  en2r     = (float*)(ws + P_EN2);
    double* partials = (double*)(ws + P_PART);

    econv_en2_kernel<<<(K_N * 32) / 256, 256, 0, stream>>>(E, Esw, en2r);
    dist14_kernel<<<B_N / 32, 256, 0, stream>>>(
        X, (const char*)Esw, en2r, top2);
    rescore_kernel<<<512, 256, 0, stream>>>(X, E, top2, out, partials);
    finalize_kernel<<<1, 256, 0, stream>>>(partials, 512, out + (size_t)B_N * D_N);
}

// Round 15
// 138.455 us; speedup vs baseline: 1.6614x; 1.0184x over previous
//
#include <hip/hip_runtime.h>

// VQ-VAE vector quantizer: B=32768, K=4096, D=256 (fp32)
// out = [quantized (B*D floats), vq_loss (1 float)]
//
//  econv_en2: E -> NEGATED fp16 (hi only) per-(ct,q,kb) 4KB frag tiles in ws,
//             fused en2f[k] = 0.5||e||^2 + 512 (bias prefolded)
//  dist15 : dist12 structure verbatim (barrier-free, X+en2 LDS-resident,
//           E wave-private via global_load_lds 2-parity dbuf + counted vmcnt(4),
//           4 waves x 64r x 64c, packed-u32 top-2 epilogue) with X fp32->fp16
//           conversion IN-PROLOGUE (dst-ordered, conflict-free ds_writes).
//  rescore: fp64 rescore of 4 candidates -> exact winner, gather, loss partials
//  finalize: loss = 1.25 * mean((x-q)^2)

#define B_N 32768
#define K_N 4096
#define D_N 256

typedef _Float16 f16x8 __attribute__((ext_vector_type(8)));
typedef float f32x4 __attribute__((ext_vector_type(4)));
typedef unsigned int uint4v __attribute__((ext_vector_type(4)));
typedef unsigned short u16;

// ws layout (~3.1 MB)
static constexpr size_t P_TOP2 = 0;                               // 32768*2*16 = 1 MB
static constexpr size_t P_ESW  = (size_t)B_N * 2 * 16;            // +2 MB
static constexpr size_t P_EN2  = P_ESW + (size_t)K_N * D_N * 2;   // +16 KB
static constexpr size_t P_PART = P_EN2 + (size_t)K_N * 4;         // +4 KB

__device__ __forceinline__ u16 f2h(float f) {
    _Float16 h = (_Float16)f;
    return __builtin_bit_cast(u16, h);
}

__device__ __forceinline__ void gload_lds16(const void* g, void* l) {
    __builtin_amdgcn_global_load_lds(
        (const __attribute__((address_space(1))) void*)g,
        (__attribute__((address_space(3))) void*)l, 16, 0, 0);
}

#define WAITVM(N) asm volatile("s_waitcnt vmcnt(" #N ")" ::: "memory")

__device__ __forceinline__ void top2_merge(float& v0, int& i0, float& v1, int& i1,
                                           float ov0, int oi0, float ov1, int oi1) {
    bool bf_ = (ov0 < v0) || (ov0 == v0 && oi0 < i0);
    float w0v = bf_ ? ov0 : v0;  int w0i = bf_ ? oi0 : i0;
    float lv  = bf_ ? v0  : ov0; int li  = bf_ ? i0  : oi0;
    float cv  = bf_ ? ov1 : v1;  int ci  = bf_ ? oi1 : i1;
    bool tl = (lv < cv) || (lv == cv && li < ci);
    v0 = w0v; i0 = w0i;
    v1 = tl ? lv : cv; i1 = tl ? li : ci;
}

// ---------- econv_en2: E -> negated fp16 hi frags + fused 0.5||e||^2+512 ----------
// code = ct*256 + q*64 + cf*16 + llo ; d = kb*32 + lhi*8 + j
// Esw u16 idx = (((ct*4+q)*8+kb)*4 + cf)*512 + (lhi*16+llo)*8   (dist12 layout)
// en2f[code] = 0.5*||e||^2 + 512
__global__ void econv_en2_kernel(const float* __restrict__ E, u16* __restrict__ Esw,
                                 float* __restrict__ en2f) {
    const int gid = blockIdx.x * 256 + threadIdx.x;     // K_N*32 threads
    const int code = gid >> 5;
    const int d0  = (gid & 31) << 3;
    const float4 a = *reinterpret_cast<const float4*>(E + (size_t)code * D_N + d0);
    const float4 b = *reinterpret_cast<const float4*>(E + (size_t)code * D_N + d0 + 4);
    float f[8] = {a.x, a.y, a.z, a.w, b.x, b.y, b.z, b.w};
    unsigned hi[8];
    double ss = 0.0;
    #pragma unroll
    for (int j = 0; j < 8; ++j) {
        hi[j] = f2h(-f[j]);
        ss += (double)f[j] * f[j];
    }
    const int ct = code >> 8, q = (code >> 6) & 3, cf = (code >> 4) & 3, llo = code & 15;
    const int kb = d0 >> 5, lhi = (d0 & 31) >> 3, lane = lhi * 16 + llo;
    size_t base = ((size_t)(((ct * 4 + q) * 8 + kb) * 4 + cf)) * 512 + (size_t)lane * 8;
    uint4v hv;
    hv.x = hi[0] | (hi[1] << 16); hv.y = hi[2] | (hi[3] << 16);
    hv.z = hi[4] | (hi[5] << 16); hv.w = hi[6] | (hi[7] << 16);
    *reinterpret_cast<uint4v*>(Esw + base) = hv;
    // reduce ||e||^2 over the 32 threads of this code (stays within 32-lane half)
    #pragma unroll
    for (int o = 16; o; o >>= 1) ss += __shfl_xor(ss, o, 64);
    if ((gid & 31) == 0) en2f[code] = (float)(0.5 * ss) + 512.0f;
}

// ---------- dist15: dist12 main loop + in-prologue X conversion ----------
// 512 blocks, 256 thr = 4 waves (q = code quarter), wave tile 64 rows x 64 codes.
// LDS 81920 B: X fp16 [kb8][rf4][lane64][8]u16 @0 (32KB) ;
//              E stage @32768: wave q at +q*8192, parity buf 4KB each ;
//              en2 fp32[4096] @65536 (16KB, bias prefolded).
__launch_bounds__(256, 2)
__global__ void dist15_kernel(const float* __restrict__ X, const char* __restrict__ Esw,
                              const float* __restrict__ en2f, float4* __restrict__ top2) {
    __shared__ __align__(16) char lds[81920];
    const int tid  = threadIdx.x;
    const int lane = tid & 63;
    const int wid  = tid >> 6;          // 0..3 = code quarter q
    const int llo  = lane & 15, lhi = lane >> 4;
    const int rb = blockIdx.x;          // 0..511 (64-row group)

    char* ldsE = lds + 32768 + wid * 8192;

    auto STAGE_E = [&](int p) {   // stage 4KB tile (ct=p>>3, q=wid, kb=p&7) into parity p&1
        const char* es = Esw + ((size_t)(((p >> 3) * 4 + wid) * 8 + (p & 7))) * 4096;
        char* lb = ldsE + (p & 1) * 4096;
        gload_lds16(es + lane * 16,        lb);
        gload_lds16(es + 1024 + lane * 16, lb + 1024);
        gload_lds16(es + 2048 + lane * 16, lb + 2048);
        gload_lds16(es + 3072 + lane * 16, lb + 3072);
    };

    unsigned pm0[16], pm1[16];          // packed (biased-val-bits & ~63) | (ct*4+j)
    #pragma unroll
    for (int s = 0; s < 16; ++s) { pm0[s] = 0xFFFFFFFFu; pm1[s] = 0xFFFFFFFFu; }

    f32x4 acc[4][4];
    #pragma unroll
    for (int i = 0; i < 4; ++i)
        #pragma unroll
        for (int j = 0; j < 4; ++j) acc[i][j] = (f32x4){0.f, 0.f, 0.f, 0.f};

    // ---- prologue ----
    // X fp32 -> fp16 frag layout, dst-ordered: slot s = it*256+tid -> frag f=it*4+wid,
    // lane; consecutive tid write consecutive 16B -> conflict-free ds_write.
    const float* xb = X + (size_t)rb * 64 * D_N;
    #pragma unroll
    for (int it = 0; it < 8; ++it) {
        const int f  = it * 4 + wid;        // 0..31
        const int kb = f >> 2, rf = f & 3;
        const int row = rf * 16 + llo;
        const int d0  = kb * 32 + lhi * 8;
        const float4 a = *reinterpret_cast<const float4*>(xb + (size_t)row * D_N + d0);
        const float4 b = *reinterpret_cast<const float4*>(xb + (size_t)row * D_N + d0 + 4);
        float fv[8] = {a.x, a.y, a.z, a.w, b.x, b.y, b.z, b.w};
        uint4v w;
        w.x = f2h(fv[0]) | ((unsigned)f2h(fv[1]) << 16);
        w.y = f2h(fv[2]) | ((unsigned)f2h(fv[3]) << 16);
        w.z = f2h(fv[4]) | ((unsigned)f2h(fv[5]) << 16);
        w.w = f2h(fv[6]) | ((unsigned)f2h(fv[7]) << 16);
        *reinterpret_cast<uint4v*>(lds + (size_t)(it * 256 + tid) * 16) = w;
    }
    // en2 table (16KB, bias prefolded) via global_load_lds
    const char* en2c = reinterpret_cast<const char*>(en2f);
    #pragma unroll
    for (int it = 0; it < 4; ++it)
        gload_lds16(en2c + it * 4096 + tid * 16, lds + 65536 + it * 4096 + wid * 1024);
    STAGE_E(0);
    __syncthreads();    // drains ds_writes + vmcnt; X/en2/E0 visible

    const f16x8* LX = reinterpret_cast<const f16x8*>(lds);
    const float* ENL = reinterpret_cast<const float*>(lds + 65536);

    for (int ct = 0; ct < 16; ++ct) {
        float en[4];
        #pragma unroll
        for (int j = 0; j < 4; ++j)
            en[j] = ENL[ct * 256 + wid * 64 + j * 16 + llo];   // bias prefolded

        #pragma unroll
        for (int kb = 0; kb < 8; ++kb) {
            const int p = ct * 8 + kb;
            if (p < 127) { STAGE_E(p + 1); WAITVM(4); }
            else         { WAITVM(0); }

            f16x8 ev[4];
            #pragma unroll
            for (int j = 0; j < 4; ++j)
                ev[j] = *reinterpret_cast<const f16x8*>(
                    ldsE + (p & 1) * 4096 + j * 1024 + lane * 16);

            __builtin_amdgcn_s_setprio(1);
            f16x8 av[4];
            #pragma unroll
            for (int i = 0; i < 4; ++i)
                av[i] = LX[(kb * 4 + i) * 64 + lane];
            #pragma unroll
            for (int i = 0; i < 4; ++i)
                #pragma unroll
                for (int j = 0; j < 4; ++j)
                    acc[i][j] = __builtin_amdgcn_mfma_f32_16x16x32_f16(
                        av[i], ev[j], acc[i][j], 0, 0, 0);
            __builtin_amdgcn_s_setprio(0);

            if (kb == 7) {
                // packed top-2 update: 6 VALU per candidate
                #pragma unroll
                for (int i = 0; i < 4; ++i) {
                    #pragma unroll
                    for (int r = 0; r < 4; ++r) {
                        const int s = i * 4 + r;
                        #pragma unroll
                        for (int j = 0; j < 4; ++j) {
                            const float v = en[j] + acc[i][j][r];
                            const unsigned c =
                                (__float_as_uint(v) & 0xFFFFFFC0u) | (unsigned)(ct * 4 + j);
                            const unsigned loser = pm0[s] > c ? pm0[s] : c;
                            pm0[s] = pm0[s] < c ? pm0[s] : c;
                            pm1[s] = pm1[s] < loser ? pm1[s] : loser;
                        }
                    }
                }
                #pragma unroll
                for (int i = 0; i < 4; ++i)
                    #pragma unroll
                    for (int j = 0; j < 4; ++j) acc[i][j] = (f32x4){0.f, 0.f, 0.f, 0.f};
            }
        }
    }

    // decode packed -> (biased val, global idx)
    float tv0[16], tv1[16];
    int   tpk[16];
    #pragma unroll
    for (int s = 0; s < 16; ++s) {
        const unsigned a = pm0[s], b = pm1[s];
        const int t0 = (int)(a & 63u), t1 = (int)(b & 63u);
        tv0[s] = __uint_as_float(a & 0xFFFFFFC0u);
        tv1[s] = __uint_as_float(b & 0xFFFFFFC0u);
        const int g0 = (t0 >> 2) * 256 + wid * 64 + (t0 & 3) * 16 + llo;
        const int g1 = (t1 >> 2) * 256 + wid * 64 + (t1 & 3) * 16 + llo;
        tpk[s] = (g1 << 16) | g0;
    }

    // merge the 16 column-lanes (llo) via shfl butterfly
    #pragma unroll
    for (int m = 1; m <= 8; m <<= 1) {
        #pragma unroll
        for (int s = 0; s < 16; ++s) {
            float ov0 = __shfl_xor(tv0[s], m, 64);
            float ov1 = __shfl_xor(tv1[s], m, 64);
            int   opk = __shfl_xor(tpk[s], m, 64);
            float v0 = tv0[s], v1 = tv1[s];
            int i0 = tpk[s] & 0xffff, i1 = (tpk[s] >> 16) & 0xffff;
            top2_merge(v0, i0, v1, i1, ov0, opk & 0xffff, ov1, (opk >> 16) & 0xffff);
            tv0[s] = v0; tv1[s] = v1; tpk[s] = (i1 << 16) | i0;
        }
    }

    __syncthreads();
    float4* M = reinterpret_cast<float4*>(lds);   // [64 rows][4 q] (reuses X region)
    if (llo == 0) {
        #pragma unroll
        for (int i = 0; i < 4; ++i)
            #pragma unroll
            for (int r = 0; r < 4; ++r) {
                const int rowl = i * 16 + lhi * 4 + r;
                const int s = i * 4 + r;
                M[rowl * 4 + wid] = make_float4(tv0[s], __int_as_float(tpk[s] & 0xffff),
                                                tv1[s], __int_as_float((tpk[s] >> 16) & 0xffff));
            }
    }
    __syncthreads();
    if (tid < 64) {
        // pairwise merge: waves 0+1 -> entry 0, waves 2+3 -> entry 1
        #pragma unroll
        for (int h = 0; h < 2; ++h) {
            float4 A4 = M[tid * 4 + 2 * h], B4 = M[tid * 4 + 2 * h + 1];
            float v0 = A4.x, v1 = A4.z;
            int i0 = __float_as_int(A4.y), i1 = __float_as_int(A4.w);
            top2_merge(v0, i0, v1, i1, B4.x, __float_as_int(B4.y), B4.z, __float_as_int(B4.w));
            top2[(size_t)(rb * 64 + tid) * 2 + h] =
                make_float4(v0, __int_as_float(i0), v1, __int_as_float(i1));
        }
    }
}

// ---------- rescore: fp64 rescore of 4 candidates (2 per wave-pair) ----------
__global__ void rescore_kernel(const float* __restrict__ X, const float* __restrict__ E,
                               const float4* __restrict__ top2, float* __restrict__ out,
                               double* __restrict__ partials) {
    const int lane = threadIdx.x & 63;
    const int wid  = (blockIdx.x * blockDim.x + threadIdx.x) >> 6;
    const int nw   = (gridDim.x * blockDim.x) >> 6;
    double wloc = 0.0;

    for (int row = wid; row < B_N; row += nw) {
        float4 t0 = top2[(size_t)row * 2 + 0];
        float4 t1 = top2[(size_t)row * 2 + 1];
        int cand[4] = { __float_as_int(t0.y), __float_as_int(t0.w),
                        __float_as_int(t1.y), __float_as_int(t1.w) };
        const float4 xv = *reinterpret_cast<const float4*>(X + (size_t)row * D_N + lane * 4);

        double bestd = 1e300; int besti = 0x7fffffff;
        float4 beste = make_float4(0.f, 0.f, 0.f, 0.f);
        #pragma unroll
        for (int c = 0; c < 4; ++c) {
            const int k = cand[c];
            const float4 ev = *reinterpret_cast<const float4*>(E + (size_t)k * D_N + lane * 4);
            double dx = (double)xv.x - (double)ev.x;
            double dy = (double)xv.y - (double)ev.y;
            double dz = (double)xv.z - (double)ev.z;
            double dw = (double)xv.w - (double)ev.w;
            double s = dx * dx + dy * dy + dz * dz + dw * dw;
            #pragma unroll
            for (int o = 32; o; o >>= 1) s += __shfl_xor(s, o, 64);
            if (s < bestd || (s == bestd && k < besti)) { bestd = s; besti = k; beste = ev; }
        }
        *reinterpret_cast<float4*>(out + (size_t)row * D_N + lane * 4) = beste;
        wloc += bestd;
    }

    __shared__ double bsum[8];
    const int widx = threadIdx.x >> 6;
    if (lane == 0) bsum[widx] = wloc;
    __syncthreads();
    if (threadIdx.x == 0) {
        double s = 0.0;
        for (int w = 0; w < (int)(blockDim.x >> 6); ++w) s += bsum[w];
        partials[blockIdx.x] = s;
    }
}

__global__ void finalize_kernel(const double* __restrict__ partials, int n,
                                float* __restrict__ loss_out) {
    __shared__ double sm[256];
    double s = 0.0;
    for (int i = threadIdx.x; i < n; i += 256) s += partials[i];
    sm[threadIdx.x] = s;
    __syncthreads();
    for (int st = 128; st; st >>= 1) {
        if (threadIdx.x < st) sm[threadIdx.x] += sm[threadIdx.x + st];
        __syncthreads();
    }
    if (threadIdx.x == 0)
        *loss_out = (float)(1.25 * sm[0] / (double)((size_t)B_N * D_N));
}

extern "C" void kernel_launch(void* const* d_in, const int* in_sizes, int n_in,
                              void* d_out, int out_size, void* d_ws, size_t ws_size,
                              hipStream_t stream) {
    const float* X = (const float*)d_in[0];
    const float* E = (const float*)d_in[1];
    float* out = (float*)d_out;
    char* ws = (char*)d_ws;

    float4* top2     = (float4*)(ws + P_TOP2);
    u16*    Esw      = (u16*)(ws + P_ESW);
    float*  en2f     = (float*)(ws + P_EN2);
    double* partials = (double*)(ws + P_PART);

    econv_en2_kernel<<<(K_N * 32) / 256, 256, 0, stream>>>(E, Esw, en2f);
    dist15_kernel<<<B_N / 64, 256, 0, stream>>>(X, (const char*)Esw, en2f, top2);
    rescore_kernel<<<512, 256, 0, stream>>>(X, E, top2, out, partials);
    finalize_kernel<<<1, 256, 0, stream>>>(partials, 512, out + (size_t)B_N * D_N);
}